// Round 5
// baseline (988.708 us; speedup 1.0000x reference)
//
#include <hip/hip_runtime.h>
#include <stdint.h>

typedef unsigned short u16;
typedef __bf16 bf16x8 __attribute__((ext_vector_type(8)));
typedef float f32x4 __attribute__((ext_vector_type(4)));
typedef float f32x2 __attribute__((ext_vector_type(2)));

// Sizes
// x:  [16][256][64][64] fp32
// w:  [256][128][4][4]  fp32
// out:[16][128][128][128] fp32
// x_t (ws): [16][66][66][256] bf16, spatially padded by 1 with zeros
// Wk  (ws): [2 p][2 dh][8 kc][2 dw][2 q][128 co][32 ci] bf16
static const size_t XT_BYTES = (size_t)16 * 66 * 66 * 256 * 2; // 35,684,352
static const size_t WK_BYTES = (size_t)2 * 2 * 8 * 2 * 2 * 128 * 32 * 2; // 1,048,576

__device__ __forceinline__ u16 f2bf(float f) {
  unsigned u = __float_as_uint(f);
  unsigned r = (u + 0x7fff + ((u >> 16) & 1)) >> 16; // RNE
  return (u16)r;
}

// async 16B global->LDS
__device__ __forceinline__ void ld_g2l16(const u16* g, void* l) {
  __builtin_amdgcn_global_load_lds(
      (const __attribute__((address_space(1))) unsigned int*)(uintptr_t)g,
      (__attribute__((address_space(3))) unsigned int*)(unsigned int)(uintptr_t)l,
      16, 0, 0);
}

// full-rank 2-bit XOR swizzle
__device__ __forceinline__ int swz4(int row) { return (row ^ (row >> 2)) & 3; }

// ---------------- fused prep: x transpose + weight reorder ----------------
__global__ __launch_bounds__(256) void prep_all(const float* __restrict__ x,
                                                const float* __restrict__ w,
                                                u16* __restrict__ xt,
                                                u16* __restrict__ wk) {
  __shared__ __align__(16) u16 sh[64 * 264]; // [iw][ci], pitch 264
  const int t = threadIdx.x;
  const int bx = blockIdx.x;
  if (bx >= 1056) { // ---- prep_w part ----
    int id = (bx - 1056) * 256 + t; // < 524288
    int ci5 = id & 31;
    int co = (id >> 5) & 127;
    int q = (id >> 12) & 1;
    int dw = (id >> 13) & 1;
    int kc = (id >> 14) & 7;
    int dh = (id >> 17) & 1;
    int p = id >> 18;
    int ci = kc * 32 + ci5;
    int kh = 2 * dh + 1 - p;
    int kw = 2 * dw + 1 - q;
    wk[id] = f2bf(w[((ci * 128 + co) * 4 + kh) * 4 + kw]);
    return;
  }
  // ---- prep_x part ----
  const int n = bx / 66;
  const int ihp = bx - n * 66; // 0..65
  u16* xtn = xt + ((size_t)(n * 66 + ihp)) * 66 * 256;
  if (ihp == 0 || ihp == 65) {
    for (int j = 0; j < 9; ++j) {
      int idx = j * 256 + t;
      if (idx < 2112) ((uint4*)xtn)[idx] = make_uint4(0, 0, 0, 0);
    }
    return;
  }
  const int ih = ihp - 1;
  const int iw0 = (t & 15) * 4;
  const int cb = (t >> 4) * 4;  // ci quad base within each 64-group
  const int swz = (t & 3) << 3; // == ((iw>>2)&3)<<3 for this thread's iw range
  const float* xb = x + (size_t)n * 1048576 + (size_t)ih * 64 + iw0;
#pragma unroll
  for (int it = 0; it < 4; ++it) {
    int ci0 = it * 64 + cb;
    float4 v0 = *(const float4*)(xb + (size_t)(ci0 + 0) * 4096);
    float4 v1 = *(const float4*)(xb + (size_t)(ci0 + 1) * 4096);
    float4 v2 = *(const float4*)(xb + (size_t)(ci0 + 2) * 4096);
    float4 v3 = *(const float4*)(xb + (size_t)(ci0 + 3) * 4096);
    int col = ci0 ^ swz;
    ushort4 u;
    u.x = f2bf(v0.x); u.y = f2bf(v1.x); u.z = f2bf(v2.x); u.w = f2bf(v3.x);
    *(ushort4*)&sh[(iw0 + 0) * 264 + col] = u;
    u.x = f2bf(v0.y); u.y = f2bf(v1.y); u.z = f2bf(v2.y); u.w = f2bf(v3.y);
    *(ushort4*)&sh[(iw0 + 1) * 264 + col] = u;
    u.x = f2bf(v0.z); u.y = f2bf(v1.z); u.z = f2bf(v2.z); u.w = f2bf(v3.z);
    *(ushort4*)&sh[(iw0 + 2) * 264 + col] = u;
    u.x = f2bf(v0.w); u.y = f2bf(v1.w); u.z = f2bf(v2.w); u.w = f2bf(v3.w);
    *(ushort4*)&sh[(iw0 + 3) * 264 + col] = u;
  }
  __syncthreads();
#pragma unroll
  for (int j = 0; j < 8; ++j) {
    int idx = j * 256 + t;
    int iw = idx >> 5;    // 0..63
    int chunk = idx & 31; // 0..31
    uint4 v = *(const uint4*)&sh[iw * 264 + ((chunk ^ ((iw >> 2) & 3)) << 3)];
    *(uint4*)&xtn[(size_t)(iw + 1) * 256 + chunk * 8] = v;
  }
  if (t < 64) { // side borders iwp = 0, 65
    int iwp = (t >> 5) * 65;
    int chunk = t & 31;
    *(uint4*)&xtn[(size_t)iwp * 256 + chunk * 8] = make_uint4(0, 0, 0, 0);
  }
}

// ---------------- main: 512-thread block, half-pair pipeline, 2 blocks/CU ----
// Block = (n, p, 4 m-rows); 8 waves (2 co-halves x 4 m-rows). LDS 66.5 KB ->
// 2 blocks/CU (16 waves) for cross-block stall filling. A staged per half-pair
// (16 KB ping-pong, 1-half runway, L2-hot); B staged per pair (2-half runway,
// counted vmcnt at dw0 ends). No inter-phase sched_barriers: compiler pipelines
// ds_reads under MFMAs within each half. sid remap puts each n on ONE XCD.
__global__ __launch_bounds__(512, 4) void gemm_ct(const u16* __restrict__ xt,
                                                  const u16* __restrict__ wk,
                                                  const float* __restrict__ bias,
                                                  float* __restrict__ out) {
  __shared__ __align__(16) u16 As[2][8192]; // [q][co][ci32] per half, swizzled
  __shared__ __align__(16) u16 Bs[2][8448]; // [rr 0..3][iwp 0..65][ci32]
  const int t = threadIdx.x;
  const int lane = t & 63;
  const int wv = t >> 6;
  const int wm = wv >> 2, wr = wv & 3; // co-half, m-row within block
  const int quad = lane >> 4, l15 = lane & 15;

  // XCD swizzle, p innermost: each n lives on exactly one XCD (n = xcd*2+k>>5)
  const int id = blockIdx.x;
  const int sid = (id & 7) * 64 + (id >> 3);
  const int p = sid & 1;
  const int mt = (sid >> 1) & 15;
  const int n = (sid >> 5) & 15;
  const int m0 = mt * 4;

  const u16* wkp = wk + (size_t)p * 262144;
  const u16* xtn = xt + (size_t)n * (66 * 66 * 256);

  // ---- staging decomposition (source-side swizzle, linear LDS dest) ----
  int aoffs[2]; // A-half: 1024 chunks over 512 threads
#pragma unroll
  for (int it = 0; it < 2; ++it) {
    int c = it * 512 + t;
    int rr = c >> 2; // [q][co] row, co = rr & 127
    aoffs[it] = rr * 32 + ((c & 3) ^ swz4(rr & 127)) * 8;
  }
  int bsrc[3]; // B: 1056 chunks; it==2 active only for t<32
#pragma unroll
  for (int it = 0; it < 3; ++it) {
    int c = it * 512 + t;
    int rr = c / 264;
    int rem = c - 264 * rr;
    int iwp = rem >> 2;
    bsrc[it] = rr * 16896 + iwp * 256 + ((rem & 3) ^ swz4(iwp)) * 8;
  }

  // ---- fragment-read offsets (u16 units), swizzled ----
  int aoff[4]; // co-term; q adds q*4096
#pragma unroll
  for (int i = 0; i < 4; ++i) {
    int co = wm * 64 + i * 16 + l15;
    aoff[i] = co * 32 + (quad ^ swz4(co)) * 8;
  }
  int bro[3][4]; // window shifts 0,1,2
#pragma unroll
  for (int k = 0; k < 3; ++k)
#pragma unroll
    for (int j = 0; j < 4; ++j) {
      int b0 = j * 16 + l15 + k;
      bro[k][j] = wr * 2112 + b0 * 32 + (quad ^ swz4(b0)) * 8;
    }

  f32x4 acc[2][4][4];
#pragma unroll
  for (int q = 0; q < 2; ++q)
#pragma unroll
    for (int i = 0; i < 4; ++i)
#pragma unroll
      for (int j = 0; j < 4; ++j) acc[q][i][j] = (f32x4){0.f, 0.f, 0.f, 0.f};

  auto stageA = [&](int buf, int hs) { // hs = dh*16 + kc*2 + dw
    const u16* asrc = wkp + (size_t)hs * 8192;
    u16* Ad = &As[buf][0];
    ld_g2l16(asrc + aoffs[0], Ad + t * 8);
    ld_g2l16(asrc + aoffs[1], Ad + (512 + t) * 8);
  };
  auto stageB = [&](int buf, int pr) { // pr = dh*8 + kc
    const int kc = pr & 7, dh = pr >> 3;
    const u16* bbase = xtn + (size_t)(m0 + p - dh + 1) * 16896 + kc * 32;
    u16* Bd = &Bs[buf][0];
    ld_g2l16(bbase + bsrc[0], Bd + t * 8);
    ld_g2l16(bbase + bsrc[1], Bd + (512 + t) * 8);
    if (t < 32) ld_g2l16(bbase + bsrc[2], Bd + (1024 + t) * 8);
  };

#define MFMA16(ACC, AF, BF)                                              \
  do {                                                                   \
    _Pragma("unroll") for (int i = 0; i < 4; ++i)                        \
        _Pragma("unroll") for (int j = 0; j < 4; ++j)                    \
        ACC[i][j] = __builtin_amdgcn_mfma_f32_16x16x32_bf16(             \
            AF[i], BF[j], ACC[i][j], 0, 0, 0);                           \
  } while (0)

  // prologue: A(half 0) + B(pair 0)
  stageA(0, 0);
  stageB(0, 0);
  asm volatile("s_waitcnt vmcnt(0)" ::: "memory");
  __builtin_amdgcn_s_barrier();
  asm volatile("" ::: "memory");

  bf16x8 keep[4]; // shift-1 B window, shared by (q0,dw0) and (q1,dw1)
#pragma unroll 1
  for (int pr = 0; pr < 16; ++pr) {
    const u16* Bc = &Bs[pr & 1][0];
    // ---- half 0 (dw=0): read As[0]; stage A(next half) + B(next pair) ----
    {
      const u16* Ac = &As[0][0];
      stageA(1, 2 * pr + 1);
      if (pr < 15) stageB((pr + 1) & 1, pr + 1);
      __builtin_amdgcn_sched_barrier(0); // stage issued before compute reads
      bf16x8 b2[4], a0[4], a1[4];
#pragma unroll
      for (int j = 0; j < 4; ++j) keep[j] = *(const bf16x8*)(Bc + bro[1][j]);
#pragma unroll
      for (int i = 0; i < 4; ++i) a0[i] = *(const bf16x8*)(Ac + aoff[i]);
#pragma unroll
      for (int j = 0; j < 4; ++j) b2[j] = *(const bf16x8*)(Bc + bro[2][j]);
#pragma unroll
      for (int i = 0; i < 4; ++i) a1[i] = *(const bf16x8*)(Ac + 4096 + aoff[i]);
      __builtin_amdgcn_s_setprio(1);
      MFMA16(acc[0], a0, keep);
      MFMA16(acc[1], a1, b2);
      __builtin_amdgcn_s_setprio(0);
      // A(2pr+1) must land (read next half); B(pr+1) stays in flight
      if (pr < 15) {
        if (wv == 0)
          asm volatile("s_waitcnt lgkmcnt(0) vmcnt(3)" ::: "memory");
        else
          asm volatile("s_waitcnt lgkmcnt(0) vmcnt(2)" ::: "memory");
      } else {
        asm volatile("s_waitcnt lgkmcnt(0) vmcnt(0)" ::: "memory");
      }
      __builtin_amdgcn_s_barrier();
      asm volatile("" ::: "memory");
    }
    // ---- half 1 (dw=1): read As[1]; stage A(next pair's half 0) ----
    {
      const u16* Ac = &As[1][0];
      if (pr < 15) stageA(0, 2 * pr + 2);
      __builtin_amdgcn_sched_barrier(0);
      bf16x8 b0[4], a0[4], a1[4];
#pragma unroll
      for (int j = 0; j < 4; ++j) b0[j] = *(const bf16x8*)(Bc + bro[0][j]);
#pragma unroll
      for (int i = 0; i < 4; ++i) a0[i] = *(const bf16x8*)(Ac + aoff[i]);
#pragma unroll
      for (int i = 0; i < 4; ++i) a1[i] = *(const bf16x8*)(Ac + 4096 + aoff[i]);
      __builtin_amdgcn_s_setprio(1);
      MFMA16(acc[0], a0, b0);
      MFMA16(acc[1], a1, keep);
      __builtin_amdgcn_s_setprio(0);
      // A(next half0) AND B(pr+1) are both read right after this barrier
      asm volatile("s_waitcnt lgkmcnt(0) vmcnt(0)" ::: "memory");
      __builtin_amdgcn_s_barrier();
      asm volatile("" ::: "memory");
    }
  }
#undef MFMA16

  // ---- epilogue: paired-parity nontemporal float2 stores ----
  const int oh = 2 * (m0 + wr) + p;
#pragma unroll
  for (int i = 0; i < 4; ++i) {
#pragma unroll
    for (int j = 0; j < 4; ++j) {
      int l = j * 16 + l15;
#pragma unroll
      for (int r = 0; r < 4; ++r) {
        int co = wm * 64 + i * 16 + quad * 4 + r;
        float bv = bias[co];
        f32x2 v;
        v.x = acc[0][i][j][r] + bv;
        v.y = acc[1][i][j][r] + bv;
        __builtin_nontemporal_store(
            v, (f32x2*)&out[(((size_t)n * 128 + co) * 128 + oh) * 128 + 2 * l]);
      }
    }
  }
}

// ---------------- safety fallback (ws too small): direct fp32 ----------------
__global__ __launch_bounds__(256) void ct_fallback(const float* __restrict__ x,
                                                   const float* __restrict__ w,
                                                   const float* __restrict__ bias,
                                                   float* __restrict__ out) {
  size_t id = (size_t)blockIdx.x * 256 + threadIdx.x;
  if (id >= (size_t)16 * 128 * 128 * 128) return;
  int ow = (int)(id & 127), oh = (int)(id >> 7) & 127;
  int co = (int)(id >> 14) & 127, n = (int)(id >> 21);
  int pp = oh & 1, m = oh >> 1, qq = ow & 1, l = ow >> 1;
  float s = bias[co];
  for (int ci = 0; ci < 256; ++ci) {
    for (int dh = 0; dh < 2; ++dh) {
      int ih = m + pp - dh;
      if (ih < 0 || ih > 63) continue;
      int kh = 2 * dh + 1 - pp;
      for (int dw = 0; dw < 2; ++dw) {
        int iw = l + qq - dw;
        if (iw < 0 || iw > 63) continue;
        int kw = 2 * dw + 1 - qq;
        s += x[(((size_t)n * 256 + ci) * 64 + ih) * 64 + iw] *
             w[((ci * 128 + co) * 4 + kh) * 4 + kw];
      }
    }
  }
  out[id] = s;
}

extern "C" void kernel_launch(void* const* d_in, const int* in_sizes, int n_in,
                              void* d_out, int out_size, void* d_ws, size_t ws_size,
                              hipStream_t stream) {
  const float* x = (const float*)d_in[0];
  const float* w = (const float*)d_in[1];
  const float* bias = (const float*)d_in[2];
  float* out = (float*)d_out;
  if (ws_size >= XT_BYTES + WK_BYTES) {
    u16* xt = (u16*)d_ws;
    u16* wkb = (u16*)((char*)d_ws + XT_BYTES);
    hipLaunchKernelGGL(prep_all, dim3(3104), dim3(256), 0, stream, x, w, xt, wkb);
    hipLaunchKernelGGL(gemm_ct, dim3(512), dim3(512), 0, stream, xt, wkb, bias, out);
  } else {
    hipLaunchKernelGGL(ct_fallback, dim3(131072), dim3(256), 0, stream, x, w, bias, out);
  }
}

// Round 6
// 242.695 us; speedup vs baseline: 4.0739x; 4.0739x over previous
//
#include <hip/hip_runtime.h>
#include <stdint.h>

typedef unsigned short u16;
typedef __bf16 bf16x8 __attribute__((ext_vector_type(8)));
typedef float f32x4 __attribute__((ext_vector_type(4)));
typedef float f32x2 __attribute__((ext_vector_type(2)));

// Sizes
// x:  [16][256][64][64] fp32
// w:  [256][128][4][4]  fp32
// out:[16][128][128][128] fp32
// x_t (ws): [16][66][66][256] bf16, spatially padded by 1 with zeros
// Wk  (ws): [2 p][2 dh][8 kc][2 dw][2 q][128 co][32 ci] bf16
static const size_t XT_BYTES = (size_t)16 * 66 * 66 * 256 * 2; // 35,684,352
static const size_t WK_BYTES = (size_t)2 * 2 * 8 * 2 * 2 * 128 * 32 * 2; // 1,048,576

__device__ __forceinline__ u16 f2bf(float f) {
  unsigned u = __float_as_uint(f);
  unsigned r = (u + 0x7fff + ((u >> 16) & 1)) >> 16; // RNE
  return (u16)r;
}

// async 16B global->LDS
__device__ __forceinline__ void ld_g2l16(const u16* g, void* l) {
  __builtin_amdgcn_global_load_lds(
      (const __attribute__((address_space(1))) unsigned int*)(uintptr_t)g,
      (__attribute__((address_space(3))) unsigned int*)(unsigned int)(uintptr_t)l,
      16, 0, 0);
}

// full-rank 2-bit XOR swizzle
__device__ __forceinline__ int swz4(int row) { return (row ^ (row >> 2)) & 3; }

// ---------------- fused prep: x transpose + weight reorder ----------------
__global__ __launch_bounds__(256) void prep_all(const float* __restrict__ x,
                                                const float* __restrict__ w,
                                                u16* __restrict__ xt,
                                                u16* __restrict__ wk) {
  __shared__ __align__(16) u16 sh[64 * 264]; // [iw][ci], pitch 264
  const int t = threadIdx.x;
  const int bx = blockIdx.x;
  if (bx >= 1056) { // ---- prep_w part ----
    int id = (bx - 1056) * 256 + t; // < 524288
    int ci5 = id & 31;
    int co = (id >> 5) & 127;
    int q = (id >> 12) & 1;
    int dw = (id >> 13) & 1;
    int kc = (id >> 14) & 7;
    int dh = (id >> 17) & 1;
    int p = id >> 18;
    int ci = kc * 32 + ci5;
    int kh = 2 * dh + 1 - p;
    int kw = 2 * dw + 1 - q;
    wk[id] = f2bf(w[((ci * 128 + co) * 4 + kh) * 4 + kw]);
    return;
  }
  // ---- prep_x part ----
  const int n = bx / 66;
  const int ihp = bx - n * 66; // 0..65
  u16* xtn = xt + ((size_t)(n * 66 + ihp)) * 66 * 256;
  if (ihp == 0 || ihp == 65) {
    for (int j = 0; j < 9; ++j) {
      int idx = j * 256 + t;
      if (idx < 2112) ((uint4*)xtn)[idx] = make_uint4(0, 0, 0, 0);
    }
    return;
  }
  const int ih = ihp - 1;
  const int iw0 = (t & 15) * 4;
  const int cb = (t >> 4) * 4;  // ci quad base within each 64-group
  const int swz = (t & 3) << 3; // == ((iw>>2)&3)<<3 for this thread's iw range
  const float* xb = x + (size_t)n * 1048576 + (size_t)ih * 64 + iw0;
#pragma unroll
  for (int it = 0; it < 4; ++it) {
    int ci0 = it * 64 + cb;
    float4 v0 = *(const float4*)(xb + (size_t)(ci0 + 0) * 4096);
    float4 v1 = *(const float4*)(xb + (size_t)(ci0 + 1) * 4096);
    float4 v2 = *(const float4*)(xb + (size_t)(ci0 + 2) * 4096);
    float4 v3 = *(const float4*)(xb + (size_t)(ci0 + 3) * 4096);
    int col = ci0 ^ swz;
    ushort4 u;
    u.x = f2bf(v0.x); u.y = f2bf(v1.x); u.z = f2bf(v2.x); u.w = f2bf(v3.x);
    *(ushort4*)&sh[(iw0 + 0) * 264 + col] = u;
    u.x = f2bf(v0.y); u.y = f2bf(v1.y); u.z = f2bf(v2.y); u.w = f2bf(v3.y);
    *(ushort4*)&sh[(iw0 + 1) * 264 + col] = u;
    u.x = f2bf(v0.z); u.y = f2bf(v1.z); u.z = f2bf(v2.z); u.w = f2bf(v3.z);
    *(ushort4*)&sh[(iw0 + 2) * 264 + col] = u;
    u.x = f2bf(v0.w); u.y = f2bf(v1.w); u.z = f2bf(v2.w); u.w = f2bf(v3.w);
    *(ushort4*)&sh[(iw0 + 3) * 264 + col] = u;
  }
  __syncthreads();
#pragma unroll
  for (int j = 0; j < 8; ++j) {
    int idx = j * 256 + t;
    int iw = idx >> 5;    // 0..63
    int chunk = idx & 31; // 0..31
    uint4 v = *(const uint4*)&sh[iw * 264 + ((chunk ^ ((iw >> 2) & 3)) << 3)];
    *(uint4*)&xtn[(size_t)(iw + 1) * 256 + chunk * 8] = v;
  }
  if (t < 64) { // side borders iwp = 0, 65
    int iwp = (t >> 5) * 65;
    int chunk = t & 31;
    *(uint4*)&xtn[(size_t)iwp * 256 + chunk * 8] = make_uint4(0, 0, 0, 0);
  }
}

// ---------------- main: 512-thread block, counted-vmcnt deep pipeline --------
// Block = (n, p, 4 m-rows); 8 waves (2 co-halves x 4 m-rows), 1 block/CU
// (2 waves/SIMD is the register-structural cap: 128 acc + ~100 arch VGPRs).
// A: 2-deep, staged 1 pair ahead (L2-hot weights, ~620cyc cover).
// B: 3-deep, staged 2 PAIRS ahead (~1300+cyc runway, covers HBM misses).
// ONE barrier per pair with COUNTED vmcnt(2|3); vmcnt(0) only at last pair.
// No inter-phase fences: compiler pipelines ds_reads under MFMAs.
__global__ __launch_bounds__(512, 2) void gemm_ct(const u16* __restrict__ xt,
                                                  const u16* __restrict__ wk,
                                                  const float* __restrict__ bias,
                                                  float* __restrict__ out) {
  __shared__ __align__(16) u16 As[2][16384]; // [dw][q][co][ci32] per pair
  __shared__ __align__(16) u16 Bs[3][8448];  // [rr 0..3][iwp 0..65][ci32]
  const int t = threadIdx.x;
  const int lane = t & 63;
  const int wv = t >> 6;
  const int wm = wv >> 2, wr = wv & 3; // co-half, m-row within block
  const int quad = lane >> 4, l15 = lane & 15;

  // XCD swizzle, p innermost: each n lives on exactly one XCD
  const int id = blockIdx.x;
  const int sid = (id & 7) * 64 + (id >> 3);
  const int p = sid & 1;
  const int mt = (sid >> 1) & 15;
  const int n = (sid >> 5) & 15;
  const int m0 = mt * 4;

  const u16* wkp = wk + (size_t)p * 262144;
  const u16* xtn = xt + (size_t)n * (66 * 66 * 256);

  // ---- staging decomposition (source-side swizzle, linear LDS dest) ----
  int aoffs[4]; // A-pair: 2048 chunks over 512 threads
#pragma unroll
  for (int it = 0; it < 4; ++it) {
    int c = it * 512 + t;
    int rr = c >> 2; // [dw][q][co] row, co = rr & 127
    aoffs[it] = rr * 32 + ((c & 3) ^ swz4(rr & 127)) * 8;
  }
  int bsrc[3]; // B: 1056 chunks; it==2 active only for t<32 (wave 0)
#pragma unroll
  for (int it = 0; it < 3; ++it) {
    int c = it * 512 + t;
    int rr = c / 264;
    int rem = c - 264 * rr;
    int iwp = rem >> 2;
    bsrc[it] = rr * 16896 + iwp * 256 + ((rem & 3) ^ swz4(iwp)) * 8;
  }

  // ---- fragment-read offsets (u16 units), swizzled ----
  int aoff[4]; // co-term; (dw,q) adds (dw*2+q)*4096
#pragma unroll
  for (int i = 0; i < 4; ++i) {
    int co = wm * 64 + i * 16 + l15;
    aoff[i] = co * 32 + (quad ^ swz4(co)) * 8;
  }
  int bro[3][4]; // window shifts 0,1,2
#pragma unroll
  for (int k = 0; k < 3; ++k)
#pragma unroll
    for (int j = 0; j < 4; ++j) {
      int b0 = j * 16 + l15 + k;
      bro[k][j] = wr * 2112 + b0 * 32 + (quad ^ swz4(b0)) * 8;
    }

  f32x4 acc[2][4][4];
#pragma unroll
  for (int q = 0; q < 2; ++q)
#pragma unroll
    for (int i = 0; i < 4; ++i)
#pragma unroll
      for (int j = 0; j < 4; ++j) acc[q][i][j] = (f32x4){0.f, 0.f, 0.f, 0.f};

  auto stageA = [&](int buf, int pr) { // full pair: [2dw][2q][128co][32ci]
    const u16* asrc = wkp + (size_t)pr * 16384;
    u16* Ad = &As[buf][0];
#pragma unroll
    for (int it = 0; it < 4; ++it)
      ld_g2l16(asrc + aoffs[it], Ad + (it * 512 + t) * 8);
  };
  auto stageB = [&](int buf, int pr) { // pr = dh*8 + kc
    const int kc = pr & 7, dh = pr >> 3;
    const u16* bbase = xtn + (size_t)(m0 + p - dh + 1) * 16896 + kc * 32;
    u16* Bd = &Bs[buf][0];
    ld_g2l16(bbase + bsrc[0], Bd + t * 8);
    ld_g2l16(bbase + bsrc[1], Bd + (512 + t) * 8);
    if (t < 32) ld_g2l16(bbase + bsrc[2], Bd + (1024 + t) * 8);
  };

#define MFMA16(ACC, AF, BF)                                              \
  do {                                                                   \
    _Pragma("unroll") for (int i = 0; i < 4; ++i)                        \
        _Pragma("unroll") for (int j = 0; j < 4; ++j)                    \
        ACC[i][j] = __builtin_amdgcn_mfma_f32_16x16x32_bf16(             \
            AF[i], BF[j], ACC[i][j], 0, 0, 0);                           \
  } while (0)

  // prologue: A(pair0), B(pair0), B(pair1) -- in this issue order
  stageA(0, 0);
  stageB(0, 0);
  stageB(1, 1);

#pragma unroll 1
  for (int pr = 0; pr < 16; ++pr) {
    // need A(pr) + B(pr) landed; newer in flight = B(pr+1) (2 loads; 3 on wv0)
    if (pr < 15) {
      if (wv == 0)
        asm volatile("s_waitcnt lgkmcnt(0) vmcnt(3)" ::: "memory");
      else
        asm volatile("s_waitcnt lgkmcnt(0) vmcnt(2)" ::: "memory");
    } else {
      asm volatile("s_waitcnt lgkmcnt(0) vmcnt(0)" ::: "memory");
    }
    __builtin_amdgcn_s_barrier();
    asm volatile("" ::: "memory");
    // issue next stages immediately (target buffers were last read pre-barrier)
    if (pr < 15) stageA((pr + 1) & 1, pr + 1);
    if (pr < 14) stageB((pr + 2) % 3, pr + 2);
    __builtin_amdgcn_sched_barrier(0);

    const u16* Ac = &As[pr & 1][0];
    const u16* Bc = &Bs[pr % 3][0];
    bf16x8 keep[4], bx[4], af[4];
    // ---- (q0,dw0) = A[0] x shift1 ----
#pragma unroll
    for (int j = 0; j < 4; ++j) keep[j] = *(const bf16x8*)(Bc + bro[1][j]);
#pragma unroll
    for (int i = 0; i < 4; ++i) af[i] = *(const bf16x8*)(Ac + aoff[i]);
    __builtin_amdgcn_s_setprio(1);
    MFMA16(acc[0], af, keep);
    __builtin_amdgcn_s_setprio(0);
    // ---- (q1,dw0) = A[1] x shift2 ----
#pragma unroll
    for (int j = 0; j < 4; ++j) bx[j] = *(const bf16x8*)(Bc + bro[2][j]);
#pragma unroll
    for (int i = 0; i < 4; ++i) af[i] = *(const bf16x8*)(Ac + 4096 + aoff[i]);
    __builtin_amdgcn_s_setprio(1);
    MFMA16(acc[1], af, bx);
    __builtin_amdgcn_s_setprio(0);
    // ---- (q0,dw1) = A[2] x shift0 ----
#pragma unroll
    for (int j = 0; j < 4; ++j) bx[j] = *(const bf16x8*)(Bc + bro[0][j]);
#pragma unroll
    for (int i = 0; i < 4; ++i) af[i] = *(const bf16x8*)(Ac + 8192 + aoff[i]);
    __builtin_amdgcn_s_setprio(1);
    MFMA16(acc[0], af, bx);
    __builtin_amdgcn_s_setprio(0);
    // ---- (q1,dw1) = A[3] x shift1 (keep) ----
#pragma unroll
    for (int i = 0; i < 4; ++i) af[i] = *(const bf16x8*)(Ac + 12288 + aoff[i]);
    __builtin_amdgcn_s_setprio(1);
    MFMA16(acc[1], af, keep);
    __builtin_amdgcn_s_setprio(0);
  }
#undef MFMA16

  // ---- epilogue: paired-parity nontemporal float2 stores ----
  const int oh = 2 * (m0 + wr) + p;
#pragma unroll
  for (int i = 0; i < 4; ++i) {
#pragma unroll
    for (int j = 0; j < 4; ++j) {
      int l = j * 16 + l15;
#pragma unroll
      for (int r = 0; r < 4; ++r) {
        int co = wm * 64 + i * 16 + quad * 4 + r;
        float bv = bias[co];
        f32x2 v;
        v.x = acc[0][i][j][r] + bv;
        v.y = acc[1][i][j][r] + bv;
        __builtin_nontemporal_store(
            v, (f32x2*)&out[(((size_t)n * 128 + co) * 128 + oh) * 128 + 2 * l]);
      }
    }
  }
}

// ---------------- safety fallback (ws too small): direct fp32 ----------------
__global__ __launch_bounds__(256) void ct_fallback(const float* __restrict__ x,
                                                   const float* __restrict__ w,
                                                   const float* __restrict__ bias,
                                                   float* __restrict__ out) {
  size_t id = (size_t)blockIdx.x * 256 + threadIdx.x;
  if (id >= (size_t)16 * 128 * 128 * 128) return;
  int ow = (int)(id & 127), oh = (int)(id >> 7) & 127;
  int co = (int)(id >> 14) & 127, n = (int)(id >> 21);
  int pp = oh & 1, m = oh >> 1, qq = ow & 1, l = ow >> 1;
  float s = bias[co];
  for (int ci = 0; ci < 256; ++ci) {
    for (int dh = 0; dh < 2; ++dh) {
      int ih = m + pp - dh;
      if (ih < 0 || ih > 63) continue;
      int kh = 2 * dh + 1 - pp;
      for (int dw = 0; dw < 2; ++dw) {
        int iw = l + qq - dw;
        if (iw < 0 || iw > 63) continue;
        int kw = 2 * dw + 1 - qq;
        s += x[(((size_t)n * 256 + ci) * 64 + ih) * 64 + iw] *
             w[((ci * 128 + co) * 4 + kh) * 4 + kw];
      }
    }
  }
  out[id] = s;
}

extern "C" void kernel_launch(void* const* d_in, const int* in_sizes, int n_in,
                              void* d_out, int out_size, void* d_ws, size_t ws_size,
                              hipStream_t stream) {
  const float* x = (const float*)d_in[0];
  const float* w = (const float*)d_in[1];
  const float* bias = (const float*)d_in[2];
  float* out = (float*)d_out;
  if (ws_size >= XT_BYTES + WK_BYTES) {
    u16* xt = (u16*)d_ws;
    u16* wkb = (u16*)((char*)d_ws + XT_BYTES);
    hipLaunchKernelGGL(prep_all, dim3(3104), dim3(256), 0, stream, x, w, xt, wkb);
    hipLaunchKernelGGL(gemm_ct, dim3(512), dim3(512), 0, stream, xt, wkb, bias, out);
  } else {
    hipLaunchKernelGGL(ct_fallback, dim3(131072), dim3(256), 0, stream, x, w, bias, out);
  }
}